// Round 4
// baseline (148305.139 us; speedup 1.0000x reference)
//
#include <hip/hip_runtime.h>

typedef unsigned short u16;
typedef unsigned int u32;
typedef unsigned long long u64;
typedef __attribute__((ext_vector_type(8))) short bf16x8;   // 8 bf16 (4 VGPRs)
typedef __attribute__((ext_vector_type(4))) float f32x4;

#define T_STEPS 1024
#define E_SZ 128
#define U_SZ 256

#define NG 16    // batch groups (16 batches each)
#define MB 16    // batch rows per group
#define NSL 8    // slices per layer (8 L0-wgs + 8 L1-wgs per group)
#define RD 8     // h0 ring depth
#define HS 264   // padded LDS row stride, K=256
#define EPAD 136 // padded LDS row stride, K=128
#define BSTRIDE 192  // u64 per slice-block: 16 batches x 12 tagged u64

#define POLL_BAIL 200000   // ~80x margin over any legit wait; latched on trip

// ---- LDS layout (role-dependent), bytes ----
#define L0_W0T 0
#define L0_R0T 34816
#define L0_X   102400
#define L0_G   106752
#define L0_B   116480
#define L1_W1T 0
#define L1_R1T 67584
#define L1_EPI 135168
#define L1_G   143616
#define L1_B   153344
#define SMEM_TOTAL 153856

// ---- exchange state: self-verifying tagged u64 = {3x bf16 | tag16} ----
// tag = run*1024 + t + 1 (mod 2^16). All exchange traffic is XCD-local
// (groups are formed per-XCD at runtime), so sc0-only (L1-bypass) ops meet
// at the shared XCD L2 instead of the MALL: RT ~200-300cy vs ~2-3k cy.
__device__ u64 g_exH0[RD * NG * NSL * BSTRIDE];  // 1.5 MiB h0 ring
__device__ u64 g_exH1[2 * NG * NSL * BSTRIDE];   // h1 parity ring
__device__ int g_pr[NG * NSL * 16];              // L1 consume progress (ring guard)
__device__ u32 g_xcdCnt[8];                      // per-XCD rank negotiation
__device__ u32 g_run;                            // run/generation counter
__device__ int g_isF32;

__device__ __forceinline__ float bf2f(u16 u) {
  union { u32 i; float f; } v; v.i = ((u32)u) << 16; return v.f;
}
__device__ __forceinline__ u16 f2bf(float f) {
  union { u32 i; float f; } v; v.f = f;
  u32 r = v.i + 0x7fffu + ((v.i >> 16) & 1u);
  return (u16)(r >> 16);
}
__device__ __forceinline__ float sig_(float x) { return 1.f / (1.f + __expf(-x)); }
__device__ __forceinline__ float tnh_(float x) { return 2.f / (1.f + __expf(-2.f * x)) - 1.f; }

// ---- sc0-only (L1-bypass, L2-service) memory ops for XCD-local exchange ----
__device__ __forceinline__ u64 ldL2(const u64* p) {        // issue only
  u64 v;
  asm volatile("global_load_dwordx2 %0, %1, off sc0" : "=v"(v) : "v"(p));
  return v;
}
__device__ __forceinline__ u64 ldL2w(const u64* p) {       // issue + wait
  u64 v;
  asm volatile("global_load_dwordx2 %0, %1, off sc0\n\ts_waitcnt vmcnt(0)"
               : "=v"(v) : "v"(p) : "memory");
  return v;
}
__device__ __forceinline__ int ldL2i(const int* p) {
  int v;
  asm volatile("global_load_dword %0, %1, off sc0\n\ts_waitcnt vmcnt(0)"
               : "=v"(v) : "v"(p) : "memory");
  return v;
}
__device__ __forceinline__ void stL2(u64* p, u64 v) {
  asm volatile("global_store_dwordx2 %0, %1, off sc0" : : "v"(p), "v"(v) : "memory");
}
__device__ __forceinline__ void stL2i(int* p, int v) {
  asm volatile("global_store_dword %0, %1, off sc0" : : "v"(p), "v"(v) : "memory");
}
__device__ __forceinline__ void waitVM() {
  asm volatile("s_waitcnt vmcnt(0)" ::: "memory");
  __builtin_amdgcn_sched_barrier(0);   // rule #18: pin uses after the wait
}

// ---- dtype probe: bumps run counter, zeroes ring guard + rank counters ----
extern "C" __global__ void dtype_probe(const void* W0v) {
  __shared__ int cntBig;
  if (threadIdx.x == 0) cntBig = 0;
  __syncthreads();
  const u16* u = (const u16*)W0v;
  int big = 0;
  for (int i = threadIdx.x; i < 4096; i += 256)
    if ((u[i] & 0x7F80u) >= 0x4100u) big++;
  atomicAdd(&cntBig, big);
  __syncthreads();
  for (int i = threadIdx.x; i < NG * NSL * 16; i += 256) g_pr[i] = 0;
  if (threadIdx.x < 8) g_xcdCnt[threadIdx.x] = 0;
  if (threadIdx.x == 0) {
    g_isF32 = (cntBig > 100) ? 1 : 0;
    g_run = g_run + 1;               // fresh tag generation each launch
  }
}

// ---- ring-guard poll returning min observed progress (amortizes re-polls) ----
__device__ __forceinline__ int wavePollMin(const int* fA, int tgt, int lane,
                                           int& dead) {
  if (dead) return tgt;              // protocol already broken: fast-fail
  const int* p = (lane < 8) ? fA + lane * 16 : nullptr;
  int ok = (p == nullptr);
  int v = 0x7fffffff;
  int it = 0;
  while (!__all(ok)) {
    if (!ok) {
      v = ldL2i(p);
      ok = v >= tgt;
    }
    if (++it > POLL_BAIL) { dead = 1; break; }
    if (it > 48) __builtin_amdgcn_s_sleep(1);
  }
  __atomic_signal_fence(__ATOMIC_ACQUIRE);
  int m = (lane < 8) ? v : 0x7fffffff;
#pragma unroll
  for (int off = 4; off; off >>= 1) {
    int o = __shfl_down(m, off);
    m = m < o ? m : o;
  }
  return __shfl(m, 0);
}

// ---- tagged gather: poll-on-data, 3 u64 per (batch=ml, quad) per slice.
// Payload layout per batch row: 12 u64 = 4 quads x 3; quad q covers k=8q..8q+7
// as {k0,k1,k2|tag}{k3,k4,k5|tag}{k6,k7,-|tag}. One L2 RT when ready. ----
__device__ __forceinline__ void loadSlices(const u64* __restrict__ base,
                                           u32 etag, int ml, int quad,
                                           bf16x8* fr, int& dead) {
  u64 A[NSL], Bq[NSL], Cq[NSL];
  const u64* p0 = base + ml * 12 + quad * 3;
#pragma unroll
  for (int j = 0; j < NSL; j++) {
    const u64* p = p0 + j * BSTRIDE;
    A[j]  = ldL2(p);
    Bq[j] = ldL2(p + 1);
    Cq[j] = ldL2(p + 2);
  }
  waitVM();
  int it = 0;
  while (true) {
    u32 bad = 0;
#pragma unroll
    for (int j = 0; j < NSL; j++) {
      u32 x = ((u32)(A[j] >> 48)) ^ etag;
      x |= ((u32)(Bq[j] >> 48)) ^ etag;
      x |= ((u32)(Cq[j] >> 48)) ^ etag;
      bad |= (x != 0 ? 1u : 0u) << j;
    }
    if (!__any(bad != 0)) break;
    if (dead) break;                  // latched: no more spinning anywhere
    if (++it > POLL_BAIL) { dead = 1; break; }   // -> fast wrong answer
#pragma unroll
    for (int j = 0; j < NSL; j++)
      if (bad & (1u << j)) {
        const u64* p = p0 + j * BSTRIDE;
        A[j]  = ldL2(p);
        Bq[j] = ldL2(p + 1);
        Cq[j] = ldL2(p + 2);
      }
    if (it > 8) __builtin_amdgcn_s_sleep(1);   // sleep overlaps reload flight
    waitVM();
  }
#pragma unroll
  for (int j = 0; j < NSL; j++) {
    u32 a0 = (u32)A[j],  a1 = (u32)(A[j] >> 32);
    u32 b0 = (u32)Bq[j], b1 = (u32)(Bq[j] >> 32);
    u32 c0 = (u32)Cq[j];
    union { u32 w[4]; bf16x8 v; } F;
    F.w[0] = a0;
    F.w[1] = (a1 & 0xFFFFu) | (b0 << 16);
    F.w[2] = (b0 >> 16) | (b1 << 16);
    F.w[3] = c0;
    fr[j] = F.v;
  }
}

extern "C" __global__ void __launch_bounds__(256, 1)
lstm_fused(const int* __restrict__ tokens, const void* __restrict__ emb,
           const void* __restrict__ W0, const void* __restrict__ R0, const void* __restrict__ b0,
           const void* __restrict__ W1, const void* __restrict__ R1, const void* __restrict__ b1,
           const void* __restrict__ Wout, const void* __restrict__ bout,
           void* __restrict__ outv) {
  extern __shared__ char smem[];

  const int tid = threadIdx.x;

  // ---- per-XCD group formation: 256 blocks are 1/CU co-resident (LDS-forced)
  // => exactly 32 blocks per XCD. Claim a rank on this XCD; the 16 wgs of a
  // group are then XCD-local, so sc0 exchange meets at the shared L2. ----
  __shared__ int s_rank;
  if (tid == 0) {
    u32 xcc;
    asm volatile("s_getreg_b32 %0, hwreg(HW_REG_XCC_ID)" : "=s"(xcc));
    xcc &= 7;
    u32 r = atomicAdd(&g_xcdCnt[xcc], 1u);
    s_rank = (int)(xcc * 32 + (r & 31));
  }
  __syncthreads();
  const int rank = s_rank;
  const int g = (rank >> 4) & (NG - 1);   // 2 groups per XCD
  const int role = (rank >> 3) & 1;       // 0 = layer-0 wg, 1 = layer-1 wg
  const int sl = rank & 7;
  const int isF32 = g_isF32;
  const u32 tagB = ((u32)g_run) << 10;

  auto ldf = [&](const void* p, int idx) -> float {
    return isF32 ? ((const float*)p)[idx] : bf2f(((const u16*)p)[idx]);
  };

  const int lane = tid & 63;
  const int wv = tid >> 6;            // wave = gate q (output tiles 2wv, 2wv+1)
  const int ml = lane & 15;
  const int quad = lane >> 4;
  const int um = tid >> 4;
  const int un = tid & 15;

  // cell/post thread mapping: (batch mB, slot uS) ; slot uS<12 holds 3 (or 2)
  // consecutive units: q=uS/3, s=uS%3, kb=8q+3s (s<2: 3 units; s==2: 2 units)
  const int mB = tid >> 4;
  const int uS = tid & 15;
  const int qS = uS / 3;
  const int sS = uS - qS * 3;
  const int kb = (qS << 3) + 3 * sS;
  const int nFull = (sS != 2);

  int* flp = g_pr + (g << 3) * 16;
  int dead = 0;

  if (role == 0) {
    // ================= LAYER-0 WORKGROUP =================
    u16* w0t = (u16*)(smem + L0_W0T);
    u16* r0t = (u16*)(smem + L0_R0T);
    u16* ldsX = (u16*)(smem + L0_X);
    float* ldsG = (float*)(smem + L0_G);
    float* ldsB = (float*)(smem + L0_B);

    for (int i = tid; i < 128 * 128; i += 256) {
      int k = i >> 7, n = i & 127;
      int col = ((n >> 5) << 8) + (sl << 5) + (n & 31);
      w0t[n * EPAD + k] = f2bf(ldf(W0, k * 1024 + col));
    }
    for (int i = tid; i < 128 * 256; i += 256) {
      int k = i >> 7, n = i & 127;
      int col = ((n >> 5) << 8) + (sl << 5) + (n & 31);
      r0t[n * HS + k] = f2bf(ldf(R0, k * 1024 + col));
    }
    if (tid < 128) {
      int col = ((tid >> 5) << 8) + (sl << 5) + (tid & 31);
      ldsB[tid] = ldf(b0, col);
    }

    float cst[3] = {0.f, 0.f, 0.f};
    const int tokBase = (g * MB + um) * T_STEPS;
    int prMin = 0;                    // cached min L1 progress (ring guard)

    float4 xfA, xfB; uint4 xbf;
    {
      int tok = tokens[tokBase];
      if (isF32) {
        const float* row = (const float*)emb + (u64)tok * E_SZ + (un << 3);
        xfA = *(const float4*)row; xfB = *(const float4*)(row + 4);
      } else {
        xbf = *(const uint4*)((const u16*)emb + (u64)tok * E_SZ + (un << 3));
      }
    }
    __syncthreads();

    const int row0 = (wv << 5) + ml;
    const u16* brA0 = w0t + row0 * EPAD + (quad << 3);
    const u16* brB0 = brA0 + (EPAD << 4);
    const u16* brA2 = r0t + row0 * HS + (quad << 3);
    const u16* brB2 = brA2 + (HS << 4);

    for (int t = 0; t < T_STEPS; t++) {
      // commit x_t
      {
        uint4 pk;
        if (isF32) {
          pk.x = (u32)f2bf(xfA.x) | ((u32)f2bf(xfA.y) << 16);
          pk.y = (u32)f2bf(xfA.z) | ((u32)f2bf(xfA.w) << 16);
          pk.z = (u32)f2bf(xfB.x) | ((u32)f2bf(xfB.y) << 16);
          pk.w = (u32)f2bf(xfB.z) | ((u32)f2bf(xfB.w) << 16);
        } else pk = xbf;
        *(uint4*)(ldsX + um * EPAD + (un << 3)) = pk;
      }
      __syncthreads();

      float ba = ldsB[row0], bb = ldsB[row0 + 16];
      f32x4 acA = {ba, ba, ba, ba}, acB = {bb, bb, bb, bb};

      // x_t @ W0 (no dependence on h0)
      {
        const u16* ar = ldsX + ml * EPAD + (quad << 3);
#pragma unroll
        for (int kc = 0; kc < 4; kc++) {
          bf16x8 av = *(const bf16x8*)(ar + kc * 32);
          acA = __builtin_amdgcn_mfma_f32_16x16x32_bf16(av, *(const bf16x8*)(brA0 + kc * 32), acA, 0, 0, 0);
          acB = __builtin_amdgcn_mfma_f32_16x16x32_bf16(av, *(const bf16x8*)(brB0 + kc * 32), acB, 0, 0, 0);
        }
      }

      // h0_{t-1} @ R0: poll-on-data tagged gather (XCD-L2 RT when ready)
      if (t > 0) {
        bf16x8 fr[NSL];
        const u64* base = g_exH0 +
            (u64)((((t - 1) & (RD - 1)) * NG + g) * NSL) * BSTRIDE;
        loadSlices(base, (tagB + t) & 0xFFFFu, ml, quad, fr, dead);
#pragma unroll
        for (int j = 0; j < NSL; j++) {
          acA = __builtin_amdgcn_mfma_f32_16x16x32_bf16(fr[j], *(const bf16x8*)(brA2 + (j << 5)), acA, 0, 0, 0);
          acB = __builtin_amdgcn_mfma_f32_16x16x32_bf16(fr[j], *(const bf16x8*)(brB2 + (j << 5)), acB, 0, 0, 0);
        }
      }

      // gates
#pragma unroll
      for (int r = 0; r < 4; r++) {
        int m = (quad << 2) + r;
        float gA = (wv == 2) ? tnh_(acA[r]) : sig_(acA[r]);
        float gB = (wv == 2) ? tnh_(acB[r]) : sig_(acB[r]);
        ldsG[row0 * 17 + m] = gA;
        ldsG[(row0 + 16) * 17 + m] = gB;
      }
      __syncthreads();

      // ring guard, amortized: re-poll only when cached slack is spent
      if (t >= RD && prMin < t - RD + 1)
        prMin = wavePollMin(flp, t - RD + 1, lane, dead);

      // cell update -> direct tagged post (fire-and-forget, no fence/flag)
      if (uS < 12) {
        u64 val = ((u64)((tagB + t + 1) & 0xFFFFu)) << 48;
#pragma unroll
        for (int i2 = 0; i2 < 3; i2++) {
          if (i2 < 2 || nFull) {
            int k = kb + i2;
            float iv = ldsG[k * 17 + mB];
            float fv = ldsG[(32 + k) * 17 + mB];
            float gv = ldsG[(64 + k) * 17 + mB];
            float ov = ldsG[(96 + k) * 17 + mB];
            float c = fv * cst[i2] + iv * gv; cst[i2] = c;
            val |= ((u64)f2bf(ov * tnh_(c))) << (16 * i2);
          }
        }
        u64 elem = (u64)(((t & (RD - 1)) * NG + g) * NSL + sl) * BSTRIDE +
                   mB * 12 + uS;
        stL2(g_exH0 + elem, val);
      }

      // x_{t+1} prefetch in flight across next rendezvous
      if (t + 1 < T_STEPS) {
        int tok = tokens[tokBase + t + 1];
        if (isF32) {
          const float* row = (const float*)emb + (u64)tok * E_SZ + (un << 3);
          xfA = *(const float4*)row; xfB = *(const float4*)(row + 4);
        } else {
          xbf = *(const uint4*)((const u16*)emb + (u64)tok * E_SZ + (un << 3));
        }
      }
    }
  } else {
    // ================= LAYER-1 WORKGROUP =================
    u16* w1t = (u16*)(smem + L1_W1T);
    u16* r1t = (u16*)(smem + L1_R1T);
    u16* ldsEpi = (u16*)(smem + L1_EPI);
    float* ldsG = (float*)(smem + L1_G);
    float* ldsB = (float*)(smem + L1_B);

    for (int i = tid; i < 128 * 256; i += 256) {
      int k = i >> 7, n = i & 127;
      int col = ((n >> 5) << 8) + (sl << 5) + (n & 31);
      w1t[n * HS + k] = f2bf(ldf(W1, k * 1024 + col));
      r1t[n * HS + k] = f2bf(ldf(R1, k * 1024 + col));
    }
    if (tid < 128) {
      int col = ((tid >> 5) << 8) + (sl << 5) + (tid & 31);
      ldsB[tid] = ldf(b1, col);
    }
    __syncthreads();

    float cst[3] = {0.f, 0.f, 0.f};
    const int row0 = (wv << 5) + ml;
    const u16* brA1 = w1t + row0 * HS + (quad << 3);
    const u16* brB1 = brA1 + (HS << 4);
    const u16* brA2 = r1t + row0 * HS + (quad << 3);
    const u16* brB2 = brA2 + (HS << 4);

    for (int t = 0; t < T_STEPS; t++) {
      float ba = ldsB[row0], bb = ldsB[row0 + 16];
      f32x4 acA = {ba, ba, ba, ba}, acB = {bb, bb, bb, bb};

      // PHASE 1: h0_t (L0 runs ahead via ring; tagged gather = 1 L2 RT)
      {
        bf16x8 fr0[NSL];
        const u64* base = g_exH0 +
            (u64)(((t & (RD - 1)) * NG + g) * NSL) * BSTRIDE;
        loadSlices(base, (tagB + t + 1) & 0xFFFFu, ml, quad, fr0, dead);
#pragma unroll
        for (int j = 0; j < NSL; j++) {
          acA = __builtin_amdgcn_mfma_f32_16x16x32_bf16(fr0[j], *(const bf16x8*)(brA1 + (j << 5)), acA, 0, 0, 0);
          acB = __builtin_amdgcn_mfma_f32_16x16x32_bf16(fr0[j], *(const bf16x8*)(brB1 + (j << 5)), acB, 0, 0, 0);
        }
      }

      // PHASE 2: h1_{t-1} rendezvous — pacing hop, single L2 RT on data
      if (t > 0) {
        bf16x8 fr1[NSL];
        const u64* base = g_exH1 +
            (u64)((((t - 1) & 1) * NG + g) * NSL) * BSTRIDE;
        loadSlices(base, (tagB + t) & 0xFFFFu, ml, quad, fr1, dead);
#pragma unroll
        for (int j = 0; j < NSL; j++) {
          acA = __builtin_amdgcn_mfma_f32_16x16x32_bf16(fr1[j], *(const bf16x8*)(brA2 + (j << 5)), acA, 0, 0, 0);
          acB = __builtin_amdgcn_mfma_f32_16x16x32_bf16(fr1[j], *(const bf16x8*)(brB2 + (j << 5)), acB, 0, 0, 0);
        }
      }

      // gates
#pragma unroll
      for (int r = 0; r < 4; r++) {
        int m = (quad << 2) + r;
        float gA = (wv == 2) ? tnh_(acA[r]) : sig_(acA[r]);
        float gB = (wv == 2) ? tnh_(acB[r]) : sig_(acB[r]);
        ldsG[row0 * 17 + m] = gA;
        ldsG[(row0 + 16) * 17 + m] = gB;
      }
      __syncthreads();

      // ring-slot release (all waves' h0 loads are consumed by now)
      if (tid == 0) {
        __atomic_signal_fence(__ATOMIC_RELEASE);
        stL2i(g_pr + ((g << 3) + sl) * 16, t + 1);
      }

      // cell update -> direct tagged post
      if (uS < 12) {
        u64 val = ((u64)((tagB + t + 1) & 0xFFFFu)) << 48;
#pragma unroll
        for (int i2 = 0; i2 < 3; i2++) {
          if (i2 < 2 || nFull) {
            int k = kb + i2;
            float iv = ldsG[k * 17 + mB];
            float fv = ldsG[(32 + k) * 17 + mB];
            float gv = ldsG[(64 + k) * 17 + mB];
            float ov = ldsG[(96 + k) * 17 + mB];
            float c = fv * cst[i2] + iv * gv; cst[i2] = c;
            val |= ((u64)f2bf(ov * tnh_(c))) << (16 * i2);
          }
        }
        u64 elem = (u64)(((t & 1) * NG + g) * NSL + sl) * BSTRIDE +
                   mB * 12 + uS;
        stL2(g_exH1 + elem, val);
      }
      __syncthreads();   // protects ldsG(t) reads vs gate writes(t+1)
    }

    // epilogue: logits from h1_{T-1}
    if (sl == 0) {
      const u32 etag = (tagB + T_STEPS) & 0xFFFFu;
      if (uS < 12) {
        for (int sp = 0; sp < 8; sp++) {
          const u64* p = g_exH1 +
              (u64)(((1) * NG + g) * NSL + sp) * BSTRIDE + mB * 12 + uS;
          u64 v; int it = 0;
          while (true) {
            v = ldL2w(p);
            if ((u32)(v >> 48) == etag) break;
            if (dead) break;
            if (++it > POLL_BAIL) { dead = 1; break; }
            if (it > 8) __builtin_amdgcn_s_sleep(1);
          }
          u16* dst = ldsEpi + mB * HS + (sp << 5) + kb;
          dst[0] = (u16)v;
          dst[1] = (u16)(v >> 16);
          if (nFull) dst[2] = (u16)(v >> 32);
        }
      }
      __syncthreads();
      float* woutf = ldsG;
      float* red = ldsG + 272;
      woutf[tid] = ldf(Wout, tid);
      __syncthreads();
      float p = 0.f;
#pragma unroll
      for (int j = 0; j < 16; j++)
        p += bf2f(ldsEpi[um * HS + (un << 4) + j]) * woutf[(un << 4) + j];
      red[um * 17 + un] = p;
      __syncthreads();
      if (tid < 16) {
        float sum = ldf(bout, 0);
#pragma unroll
        for (int j = 0; j < 16; j++) sum += red[tid * 17 + j];
        float val = sig_(sum);
        if (isF32) ((float*)outv)[g * MB + tid] = val;
        else       ((u16*)outv)[g * MB + tid] = f2bf(val);
      }
    }
  }
}

extern "C" void kernel_launch(void* const* d_in, const int* in_sizes, int n_in,
                              void* d_out, int out_size, void* d_ws, size_t ws_size,
                              hipStream_t stream) {
  const int* tokens = (const int*)d_in[0];
  const void* emb  = d_in[1];
  const void* W0   = d_in[2];
  const void* R0   = d_in[3];
  const void* b0   = d_in[4];
  const void* W1   = d_in[5];
  const void* R1   = d_in[6];
  const void* b1   = d_in[7];
  const void* Wout = d_in[8];
  const void* bout = d_in[9];

  hipFuncSetAttribute((const void*)lstm_fused,
                      hipFuncAttributeMaxDynamicSharedMemorySize, SMEM_TOTAL);

  dtype_probe<<<dim3(1), dim3(256), 0, stream>>>(W0);

  // 256 wgs (16 groups x (8 L0 + 8 L1)), 1 wg/CU: co-resident; groups are
  // re-formed per-XCD at runtime so all exchange is XCD-L2-local.
  lstm_fused<<<dim3(256), dim3(256), SMEM_TOTAL, stream>>>(
      tokens, emb, W0, R0, b0, W1, R1, b1, Wout, bout, d_out);
}

// Round 6
// 4832.236 us; speedup vs baseline: 30.6908x; 30.6908x over previous
//
#include <hip/hip_runtime.h>

typedef unsigned short u16;
typedef unsigned int u32;
typedef unsigned long long u64;
typedef __attribute__((ext_vector_type(8))) short bf16x8;   // 8 bf16 (4 VGPRs)
typedef __attribute__((ext_vector_type(4))) float f32x4;

#define T_STEPS 1024
#define E_SZ 128
#define U_SZ 256

#define NG 16    // batch groups (16 batches each)
#define MB 16    // batch rows per group
#define NSL 8    // slices per layer (8 L0-wgs + 8 L1-wgs per group)
#define RD 8     // h0 ring depth
#define HS 264   // padded LDS row stride, K=256
#define EPAD 136 // padded LDS row stride, K=128
#define BSTRIDE 192  // u64 per slice-block: 16 batches x 12 tagged u64

#define POLL_BAIL 60000   // latched fast-fail: broken protocol -> quick wrong answer

// ---- LDS layout (role-dependent), bytes ----
#define L0_W0T 0
#define L0_R0T 34816
#define L0_X   102400
#define L0_G   106752
#define L0_B   116480
#define L1_W1T 0
#define L1_R1T 67584
#define L1_EPI 135168
#define L1_G   143616
#define L1_B   153344
#define SMEM_TOTAL 153856

// ---- exchange state: self-verifying tagged u64 = {3x bf16 | tag16} ----
// tag = run*1024 + t + 1 (mod 2^16). Agent scope (MALL-serviced): the only
// HW-verified fast producer->consumer channel on this chip (R2: 4733us;
// R4's sc0/XCD-local variant failed visibility -> 148ms).
__device__ u64 g_exH0[RD * NG * NSL * BSTRIDE];  // 1.5 MiB h0 ring
__device__ u64 g_exH1[2 * NG * NSL * BSTRIDE];   // h1 parity ring
__device__ int g_pr[NG * NSL * 16];              // L1 consume progress (ring guard)
__device__ u32 g_run;                            // run/generation counter
__device__ int g_isF32;

__device__ __forceinline__ float bf2f(u16 u) {
  union { u32 i; float f; } v; v.i = ((u32)u) << 16; return v.f;
}
__device__ __forceinline__ u16 f2bf(float f) {
  union { u32 i; float f; } v; v.f = f;
  u32 r = v.i + 0x7fffu + ((v.i >> 16) & 1u);
  return (u16)(r >> 16);
}
__device__ __forceinline__ float sig_(float x) { return 1.f / (1.f + __expf(-x)); }
__device__ __forceinline__ float tnh_(float x) { return 2.f / (1.f + __expf(-2.f * x)) - 1.f; }

// ---- dtype probe: bumps run counter, zeroes ring guard ----
extern "C" __global__ void dtype_probe(const void* W0v) {
  __shared__ int cntBig;
  if (threadIdx.x == 0) cntBig = 0;
  __syncthreads();
  const u16* u = (const u16*)W0v;
  int big = 0;
  for (int i = threadIdx.x; i < 4096; i += 256)
    if ((u[i] & 0x7F80u) >= 0x4100u) big++;
  atomicAdd(&cntBig, big);
  __syncthreads();
  for (int i = threadIdx.x; i < NG * NSL * 16; i += 256) g_pr[i] = 0;
  if (threadIdx.x == 0) {
    g_isF32 = (cntBig > 100) ? 1 : 0;
    g_run = g_run + 1;               // fresh tag generation each launch
  }
}

__device__ __forceinline__ u64 ldAtom(const u64* p) {
  return __hip_atomic_load(p, __ATOMIC_RELAXED, __HIP_MEMORY_SCOPE_AGENT);
}

// ---- ring-guard poll returning min observed progress (amortizes re-polls) ----
__device__ __forceinline__ int wavePollMin(const int* fA, int tgt, int lane,
                                           int& dead) {
  if (dead) return tgt;
  const int* p = (lane < 8) ? fA + lane * 16 : nullptr;
  int ok = (p == nullptr);
  int v = 0x7fffffff;
  int it = 0;
  while (!__all(ok)) {
    if (!ok) {
      v = __hip_atomic_load(p, __ATOMIC_RELAXED, __HIP_MEMORY_SCOPE_AGENT);
      ok = v >= tgt;
    }
    if (++it > POLL_BAIL) { dead = 1; break; }
    if (it > 48) __builtin_amdgcn_s_sleep(1);
  }
  __atomic_signal_fence(__ATOMIC_ACQUIRE);
  int m = (lane < 8) ? v : 0x7fffffff;
#pragma unroll
  for (int off = 4; off; off >>= 1) {
    int o = __shfl_down(m, off);
    m = m < o ? m : o;
  }
  return __shfl(m, 0);
}

// ---- split tagged gather: issue 24 loads early, complete (poll+unpack) late.
// Payload per batch row: 12 u64 = 4 quads x 3; quad q covers k=8q..8q+7 as
// {k0,k1,k2|tag}{k3,k4,k5|tag}{k6,k7,-|tag}. Issue/complete split lets two
// gathers' MALL RTs overlap instead of serializing. ----
struct Gather { u64 A[NSL], B[NSL], C[NSL]; };

__device__ __forceinline__ void issueSlices(const u64* __restrict__ base,
                                            int ml, int quad, Gather& gh) {
  const u64* p0 = base + ml * 12 + quad * 3;
#pragma unroll
  for (int j = 0; j < NSL; j++) {
    const u64* p = p0 + j * BSTRIDE;
    gh.A[j] = ldAtom(p);
    gh.B[j] = ldAtom(p + 1);
    gh.C[j] = ldAtom(p + 2);
  }
}

__device__ __forceinline__ void completeSlices(const u64* __restrict__ base,
                                               u32 etag, int ml, int quad,
                                               Gather& gh, bf16x8* fr,
                                               int& dead) {
  const u64* p0 = base + ml * 12 + quad * 3;
  int it = 0;
  while (true) {
    u32 bad = 0;
#pragma unroll
    for (int j = 0; j < NSL; j++) {
      u32 x = ((u32)(gh.A[j] >> 48)) ^ etag;
      x |= ((u32)(gh.B[j] >> 48)) ^ etag;
      x |= ((u32)(gh.C[j] >> 48)) ^ etag;
      bad |= (x != 0 ? 1u : 0u) << j;
    }
    if (!__any(bad != 0)) break;
    if (dead) break;
    if (++it > POLL_BAIL) { dead = 1; break; }
#pragma unroll
    for (int j = 0; j < NSL; j++)
      if (bad & (1u << j)) {
        const u64* p = p0 + j * BSTRIDE;
        gh.A[j] = ldAtom(p);
        gh.B[j] = ldAtom(p + 1);
        gh.C[j] = ldAtom(p + 2);
      }
    if (it > 8) __builtin_amdgcn_s_sleep(1);
  }
  __atomic_signal_fence(__ATOMIC_ACQUIRE);
#pragma unroll
  for (int j = 0; j < NSL; j++) {
    u32 a0 = (u32)gh.A[j], a1 = (u32)(gh.A[j] >> 32);
    u32 b0 = (u32)gh.B[j], b1 = (u32)(gh.B[j] >> 32);
    u32 c0 = (u32)gh.C[j];
    union { u32 w[4]; bf16x8 v; } F;
    F.w[0] = a0;
    F.w[1] = (a1 & 0xFFFFu) | (b0 << 16);
    F.w[2] = (b0 >> 16) | (b1 << 16);
    F.w[3] = c0;
    fr[j] = F.v;
  }
}

extern "C" __global__ void __launch_bounds__(256, 1)
lstm_fused(const int* __restrict__ tokens, const void* __restrict__ emb,
           const void* __restrict__ W0, const void* __restrict__ R0, const void* __restrict__ b0,
           const void* __restrict__ W1, const void* __restrict__ R1, const void* __restrict__ b1,
           const void* __restrict__ Wout, const void* __restrict__ bout,
           void* __restrict__ outv) {
  extern __shared__ char smem[];

  const int tid = threadIdx.x;
  const int b = blockIdx.x;
  const int g = b & (NG - 1);
  const int w = b >> 4;
  const int role = w >> 3;             // 0 = layer-0 wg, 1 = layer-1 wg
  const int sl = w & 7;
  const int isF32 = g_isF32;
  const u32 tagB = ((u32)g_run) << 10;

  auto ldf = [&](const void* p, int idx) -> float {
    return isF32 ? ((const float*)p)[idx] : bf2f(((const u16*)p)[idx]);
  };

  const int lane = tid & 63;
  const int wv = tid >> 6;            // wave = gate q (output tiles 2wv, 2wv+1)
  const int ml = lane & 15;
  const int quad = lane >> 4;
  const int um = tid >> 4;
  const int un = tid & 15;

  // cell/post thread mapping: (batch mB, slot uS) ; slot uS<12 holds 3 (or 2)
  // consecutive units: q=uS/3, s=uS%3, kb=8q+3s (s<2: 3 units; s==2: 2 units)
  const int mB = tid >> 4;
  const int uS = tid & 15;
  const int qS = uS / 3;
  const int sS = uS - qS * 3;
  const int kb = (qS << 3) + 3 * sS;
  const int nFull = (sS != 2);

  int* flp = g_pr + (g << 3) * 16;
  int dead = 0;

  if (role == 0) {
    // ================= LAYER-0 WORKGROUP =================
    u16* w0t = (u16*)(smem + L0_W0T);
    u16* r0t = (u16*)(smem + L0_R0T);
    u16* ldsX = (u16*)(smem + L0_X);
    float* ldsG = (float*)(smem + L0_G);
    float* ldsB = (float*)(smem + L0_B);

    for (int i = tid; i < 128 * 128; i += 256) {
      int k = i >> 7, n = i & 127;
      int col = ((n >> 5) << 8) + (sl << 5) + (n & 31);
      w0t[n * EPAD + k] = f2bf(ldf(W0, k * 1024 + col));
    }
    for (int i = tid; i < 128 * 256; i += 256) {
      int k = i >> 7, n = i & 127;
      int col = ((n >> 5) << 8) + (sl << 5) + (n & 31);
      r0t[n * HS + k] = f2bf(ldf(R0, k * 1024 + col));
    }
    if (tid < 128) {
      int col = ((tid >> 5) << 8) + (sl << 5) + (tid & 31);
      ldsB[tid] = ldf(b0, col);
    }

    float cst[3] = {0.f, 0.f, 0.f};
    const int tokBase = (g * MB + um) * T_STEPS;
    int prMin = 0;                    // cached min L1 progress (ring guard)

    float4 xfA, xfB; uint4 xbf;
    {
      int tok = tokens[tokBase];
      if (isF32) {
        const float* row = (const float*)emb + (u64)tok * E_SZ + (un << 3);
        xfA = *(const float4*)row; xfB = *(const float4*)(row + 4);
      } else {
        xbf = *(const uint4*)((const u16*)emb + (u64)tok * E_SZ + (un << 3));
      }
    }
    __syncthreads();

    const int row0 = (wv << 5) + ml;
    const u16* brA0 = w0t + row0 * EPAD + (quad << 3);
    const u16* brB0 = brA0 + (EPAD << 4);
    const u16* brA2 = r0t + row0 * HS + (quad << 3);
    const u16* brB2 = brA2 + (HS << 4);

    Gather gh;
    for (int t = 0; t < T_STEPS; t++) {
      // issue h0_{t-1} gather FIRST: its MALL RT overlaps x-commit + W0 MFMAs
      const u64* h0base = g_exH0 +
          (u64)((((t - 1) & (RD - 1)) * NG + g) * NSL) * BSTRIDE;
      if (t > 0) issueSlices(h0base, ml, quad, gh);

      // commit x_t
      {
        uint4 pk;
        if (isF32) {
          pk.x = (u32)f2bf(xfA.x) | ((u32)f2bf(xfA.y) << 16);
          pk.y = (u32)f2bf(xfA.z) | ((u32)f2bf(xfA.w) << 16);
          pk.z = (u32)f2bf(xfB.x) | ((u32)f2bf(xfB.y) << 16);
          pk.w = (u32)f2bf(xfB.z) | ((u32)f2bf(xfB.w) << 16);
        } else pk = xbf;
        *(uint4*)(ldsX + um * EPAD + (un << 3)) = pk;
      }
      __syncthreads();

      float ba = ldsB[row0], bb = ldsB[row0 + 16];
      f32x4 acA = {ba, ba, ba, ba}, acB = {bb, bb, bb, bb};

      // x_t @ W0 (no dependence on h0; h0 loads in flight)
      {
        const u16* ar = ldsX + ml * EPAD + (quad << 3);
#pragma unroll
        for (int kc = 0; kc < 4; kc++) {
          bf16x8 av = *(const bf16x8*)(ar + kc * 32);
          acA = __builtin_amdgcn_mfma_f32_16x16x32_bf16(av, *(const bf16x8*)(brA0 + kc * 32), acA, 0, 0, 0);
          acB = __builtin_amdgcn_mfma_f32_16x16x32_bf16(av, *(const bf16x8*)(brB0 + kc * 32), acB, 0, 0, 0);
        }
      }

      // h0_{t-1} @ R0: complete gather (poll+unpack), then MFMAs
      if (t > 0) {
        bf16x8 fr[NSL];
        completeSlices(h0base, (tagB + t) & 0xFFFFu, ml, quad, gh, fr, dead);
#pragma unroll
        for (int j = 0; j < NSL; j++) {
          acA = __builtin_amdgcn_mfma_f32_16x16x32_bf16(fr[j], *(const bf16x8*)(brA2 + (j << 5)), acA, 0, 0, 0);
          acB = __builtin_amdgcn_mfma_f32_16x16x32_bf16(fr[j], *(const bf16x8*)(brB2 + (j << 5)), acB, 0, 0, 0);
        }
      }

      // gates
#pragma unroll
      for (int r = 0; r < 4; r++) {
        int m = (quad << 2) + r;
        float gA = (wv == 2) ? tnh_(acA[r]) : sig_(acA[r]);
        float gB = (wv == 2) ? tnh_(acB[r]) : sig_(acB[r]);
        ldsG[row0 * 17 + m] = gA;
        ldsG[(row0 + 16) * 17 + m] = gB;
      }
      __syncthreads();

      // ring guard, amortized: re-poll only when cached slack is spent
      if (t >= RD && prMin < t - RD + 1)
        prMin = wavePollMin(flp, t - RD + 1, lane, dead);

      // cell update -> direct tagged post (fire-and-forget, no fence/flag)
      if (uS < 12) {
        u64 val = ((u64)((tagB + t + 1) & 0xFFFFu)) << 48;
#pragma unroll
        for (int i2 = 0; i2 < 3; i2++) {
          if (i2 < 2 || nFull) {
            int k = kb + i2;
            float iv = ldsG[k * 17 + mB];
            float fv = ldsG[(32 + k) * 17 + mB];
            float gv = ldsG[(64 + k) * 17 + mB];
            float ov = ldsG[(96 + k) * 17 + mB];
            float c = fv * cst[i2] + iv * gv; cst[i2] = c;
            val |= ((u64)f2bf(ov * tnh_(c))) << (16 * i2);
          }
        }
        u64 elem = (u64)(((t & (RD - 1)) * NG + g) * NSL + sl) * BSTRIDE +
                   mB * 12 + uS;
        __hip_atomic_store(g_exH0 + elem, val,
                           __ATOMIC_RELAXED, __HIP_MEMORY_SCOPE_AGENT);
      }

      // x_{t+1} prefetch in flight across next rendezvous
      if (t + 1 < T_STEPS) {
        int tok = tokens[tokBase + t + 1];
        if (isF32) {
          const float* row = (const float*)emb + (u64)tok * E_SZ + (un << 3);
          xfA = *(const float4*)row; xfB = *(const float4*)(row + 4);
        } else {
          xbf = *(const uint4*)((const u16*)emb + (u64)tok * E_SZ + (un << 3));
        }
      }
    }
  } else {
    // ================= LAYER-1 WORKGROUP =================
    u16* w1t = (u16*)(smem + L1_W1T);
    u16* r1t = (u16*)(smem + L1_R1T);
    u16* ldsEpi = (u16*)(smem + L1_EPI);
    float* ldsG = (float*)(smem + L1_G);
    float* ldsB = (float*)(smem + L1_B);

    for (int i = tid; i < 128 * 256; i += 256) {
      int k = i >> 7, n = i & 127;
      int col = ((n >> 5) << 8) + (sl << 5) + (n & 31);
      w1t[n * HS + k] = f2bf(ldf(W1, k * 1024 + col));
      r1t[n * HS + k] = f2bf(ldf(R1, k * 1024 + col));
    }
    if (tid < 128) {
      int col = ((tid >> 5) << 8) + (sl << 5) + (tid & 31);
      ldsB[tid] = ldf(b1, col);
    }
    __syncthreads();

    float cst[3] = {0.f, 0.f, 0.f};
    const int row0 = (wv << 5) + ml;
    const u16* brA1 = w1t + row0 * HS + (quad << 3);
    const u16* brB1 = brA1 + (HS << 4);
    const u16* brA2 = r1t + row0 * HS + (quad << 3);
    const u16* brB2 = brA2 + (HS << 4);

    Gather g0, g1;
    for (int t = 0; t < T_STEPS; t++) {
      // issue BOTH gathers back-to-back: their MALL RTs overlap
      const u64* h0base = g_exH0 +
          (u64)(((t & (RD - 1)) * NG + g) * NSL) * BSTRIDE;
      const u64* h1base = g_exH1 +
          (u64)((((t - 1) & 1) * NG + g) * NSL) * BSTRIDE;
      issueSlices(h0base, ml, quad, g0);
      if (t > 0) issueSlices(h1base, ml, quad, g1);

      float ba = ldsB[row0], bb = ldsB[row0 + 16];
      f32x4 acA = {ba, ba, ba, ba}, acB = {bb, bb, bb, bb};

      // PHASE 1: h0_t @ W1 (h1 loads still in flight during these MFMAs)
      {
        bf16x8 fr0[NSL];
        completeSlices(h0base, (tagB + t + 1) & 0xFFFFu, ml, quad, g0, fr0, dead);
#pragma unroll
        for (int j = 0; j < NSL; j++) {
          acA = __builtin_amdgcn_mfma_f32_16x16x32_bf16(fr0[j], *(const bf16x8*)(brA1 + (j << 5)), acA, 0, 0, 0);
          acB = __builtin_amdgcn_mfma_f32_16x16x32_bf16(fr0[j], *(const bf16x8*)(brB1 + (j << 5)), acB, 0, 0, 0);
        }
      }

      // PHASE 2: h1_{t-1} @ R1 — pacing hop; loads were issued at loop top
      if (t > 0) {
        bf16x8 fr1[NSL];
        completeSlices(h1base, (tagB + t) & 0xFFFFu, ml, quad, g1, fr1, dead);
#pragma unroll
        for (int j = 0; j < NSL; j++) {
          acA = __builtin_amdgcn_mfma_f32_16x16x32_bf16(fr1[j], *(const bf16x8*)(brA2 + (j << 5)), acA, 0, 0, 0);
          acB = __builtin_amdgcn_mfma_f32_16x16x32_bf16(fr1[j], *(const bf16x8*)(brB2 + (j << 5)), acB, 0, 0, 0);
        }
      }

      // gates
#pragma unroll
      for (int r = 0; r < 4; r++) {
        int m = (quad << 2) + r;
        float gA = (wv == 2) ? tnh_(acA[r]) : sig_(acA[r]);
        float gB = (wv == 2) ? tnh_(acB[r]) : sig_(acB[r]);
        ldsG[row0 * 17 + m] = gA;
        ldsG[(row0 + 16) * 17 + m] = gB;
      }
      __syncthreads();

      // ring-slot release (all waves' h0 loads are consumed by now)
      if (tid == 0) {
        __atomic_signal_fence(__ATOMIC_RELEASE);
        __hip_atomic_store(g_pr + ((g << 3) + sl) * 16, t + 1,
                           __ATOMIC_RELAXED, __HIP_MEMORY_SCOPE_AGENT);
      }

      // cell update -> direct tagged post
      if (uS < 12) {
        u64 val = ((u64)((tagB + t + 1) & 0xFFFFu)) << 48;
#pragma unroll
        for (int i2 = 0; i2 < 3; i2++) {
          if (i2 < 2 || nFull) {
            int k = kb + i2;
            float iv = ldsG[k * 17 + mB];
            float fv = ldsG[(32 + k) * 17 + mB];
            float gv = ldsG[(64 + k) * 17 + mB];
            float ov = ldsG[(96 + k) * 17 + mB];
            float c = fv * cst[i2] + iv * gv; cst[i2] = c;
            val |= ((u64)f2bf(ov * tnh_(c))) << (16 * i2);
          }
        }
        u64 elem = (u64)(((t & 1) * NG + g) * NSL + sl) * BSTRIDE +
                   mB * 12 + uS;
        __hip_atomic_store(g_exH1 + elem, val,
                           __ATOMIC_RELAXED, __HIP_MEMORY_SCOPE_AGENT);
      }
      __syncthreads();   // protects ldsG(t) reads vs gate writes(t+1)
    }

    // epilogue: logits from h1_{T-1}
    if (sl == 0) {
      const u32 etag = (tagB + T_STEPS) & 0xFFFFu;
      if (uS < 12) {
        for (int sp = 0; sp < 8; sp++) {
          const u64* p = g_exH1 +
              (u64)(((1) * NG + g) * NSL + sp) * BSTRIDE + mB * 12 + uS;
          u64 v; int it = 0;
          while (true) {
            v = ldAtom(p);
            if ((u32)(v >> 48) == etag) break;
            if (dead) break;
            if (++it > POLL_BAIL) { dead = 1; break; }
            if (it > 8) __builtin_amdgcn_s_sleep(1);
          }
          u16* dst = ldsEpi + mB * HS + (sp << 5) + kb;
          dst[0] = (u16)v;
          dst[1] = (u16)(v >> 16);
          if (nFull) dst[2] = (u16)(v >> 32);
        }
      }
      __syncthreads();
      float* woutf = ldsG;
      float* red = ldsG + 272;
      woutf[tid] = ldf(Wout, tid);
      __syncthreads();
      float p = 0.f;
#pragma unroll
      for (int j = 0; j < 16; j++)
        p += bf2f(ldsEpi[um * HS + (un << 4) + j]) * woutf[(un << 4) + j];
      red[um * 17 + un] = p;
      __syncthreads();
      if (tid < 16) {
        float sum = ldf(bout, 0);
#pragma unroll
        for (int j = 0; j < 16; j++) sum += red[tid * 17 + j];
        float val = sig_(sum);
        if (isF32) ((float*)outv)[g * MB + tid] = val;
        else       ((u16*)outv)[g * MB + tid] = f2bf(val);
      }
    }
  }
}

extern "C" void kernel_launch(void* const* d_in, const int* in_sizes, int n_in,
                              void* d_out, int out_size, void* d_ws, size_t ws_size,
                              hipStream_t stream) {
  const int* tokens = (const int*)d_in[0];
  const void* emb  = d_in[1];
  const void* W0   = d_in[2];
  const void* R0   = d_in[3];
  const void* b0   = d_in[4];
  const void* W1   = d_in[5];
  const void* R1   = d_in[6];
  const void* b1   = d_in[7];
  const void* Wout = d_in[8];
  const void* bout = d_in[9];

  hipFuncSetAttribute((const void*)lstm_fused,
                      hipFuncAttributeMaxDynamicSharedMemorySize, SMEM_TOTAL);

  dtype_probe<<<dim3(1), dim3(256), 0, stream>>>(W0);

  // 256 wgs (16 groups x (8 L0 + 8 L1)), 1 wg/CU: co-resident.
  lstm_fused<<<dim3(256), dim3(256), SMEM_TOTAL, stream>>>(
      tokens, emb, W0, R0, b0, W1, R1, b1, Wout, bout, d_out);
}

// Round 7
// 3133.481 us; speedup vs baseline: 47.3292x; 1.5421x over previous
//
#include <hip/hip_runtime.h>

typedef unsigned short u16;
typedef unsigned int u32;
typedef unsigned long long u64;
typedef __attribute__((ext_vector_type(8))) short bf16x8;   // 8 bf16 (4 VGPRs)
typedef __attribute__((ext_vector_type(4))) float f32x4;

#define T_STEPS 1024
#define E_SZ 128
#define U_SZ 256

#define NG 16    // batch groups (16 batches each)
#define MB 16    // batch rows per group
#define NSL 8    // slices per layer (8 L0-wgs + 8 L1-wgs per group)
#define RD 8     // h0 ring depth
#define HS 264   // padded LDS row stride, K=256
#define EPAD 136 // padded LDS row stride, K=128
#define BSTRIDE 192  // u64 per slice-block: 16 batches x 12 tagged u64

#define POLL_BAIL 60000   // latched fast-fail: broken protocol -> quick wrong answer

// ---- LDS layout (role-dependent), bytes ----
#define L0_W0T 0
#define L0_R0T 34816
#define L0_X   102400
#define L0_G   106752
#define L0_STG 115520
#define L0_B   123712
#define L1_W1T 0
#define L1_R1T 67584
#define L1_SG0 135168
#define L1_SG1 143360
#define L1_G   151552
#define L1_B   160320
#define SMEM_TOTAL 160832

// ---- exchange state: self-verifying tagged u64 = {3x bf16 | tag16} ----
// tag = run*1024 + t + 1 (mod 2^16). Agent scope (MALL-serviced): the only
// HW-verified fast channel (R2: 4733us). R6 lesson: issue-early on pacing
// data is useless (stale). This round: 4x traffic cut via wave-split
// staged gather (was: all 4 waves redundantly loading identical fragments
// -> ~4TB/s of MALL traffic -> queueing-inflated RTs).
__device__ u64 g_exH0[RD * NG * NSL * BSTRIDE];  // 1.5 MiB h0 ring
__device__ u64 g_exH1[2 * NG * NSL * BSTRIDE];   // h1 parity ring
__device__ int g_pr[NG * NSL * 16];              // L1 consume progress (ring guard)
__device__ u32 g_run;                            // run/generation counter
__device__ int g_isF32;

__device__ __forceinline__ float bf2f(u16 u) {
  union { u32 i; float f; } v; v.i = ((u32)u) << 16; return v.f;
}
__device__ __forceinline__ u16 f2bf(float f) {
  union { u32 i; float f; } v; v.f = f;
  u32 r = v.i + 0x7fffu + ((v.i >> 16) & 1u);
  return (u16)(r >> 16);
}
__device__ __forceinline__ float sig_(float x) { return 1.f / (1.f + __expf(-x)); }
__device__ __forceinline__ float tnh_(float x) { return 2.f / (1.f + __expf(-2.f * x)) - 1.f; }

// ---- dtype probe: bumps run counter, zeroes ring guard ----
extern "C" __global__ void dtype_probe(const void* W0v) {
  __shared__ int cntBig;
  if (threadIdx.x == 0) cntBig = 0;
  __syncthreads();
  const u16* u = (const u16*)W0v;
  int big = 0;
  for (int i = threadIdx.x; i < 4096; i += 256)
    if ((u[i] & 0x7F80u) >= 0x4100u) big++;
  atomicAdd(&cntBig, big);
  __syncthreads();
  for (int i = threadIdx.x; i < NG * NSL * 16; i += 256) g_pr[i] = 0;
  if (threadIdx.x == 0) {
    g_isF32 = (cntBig > 100) ? 1 : 0;
    g_run = g_run + 1;               // fresh tag generation each launch
  }
}

__device__ __forceinline__ u64 ldAtom(const u64* p) {
  return __hip_atomic_load(p, __ATOMIC_RELAXED, __HIP_MEMORY_SCOPE_AGENT);
}

// ---- ring-guard poll returning min observed progress (amortizes re-polls) ----
__device__ __forceinline__ int wavePollMin(const int* fA, int tgt, int lane,
                                           int& dead) {
  if (dead) return tgt;
  const int* p = (lane < 8) ? fA + lane * 16 : nullptr;
  int ok = (p == nullptr);
  int v = 0x7fffffff;
  int it = 0;
  while (!__all(ok)) {
    if (!ok) {
      v = __hip_atomic_load(p, __ATOMIC_RELAXED, __HIP_MEMORY_SCOPE_AGENT);
      ok = v >= tgt;
    }
    if (++it > POLL_BAIL) { dead = 1; break; }
    if (it > 48) __builtin_amdgcn_s_sleep(1);
  }
  __atomic_signal_fence(__ATOMIC_ACQUIRE);
  int m = (lane < 8) ? v : 0x7fffffff;
#pragma unroll
  for (int off = 4; off; off >>= 1) {
    int o = __shfl_down(m, off);
    m = m < o ? m : o;
  }
  return __shfl(m, 0);
}

// ---- unpack 3 tagged u64 -> 16B fragment, write to LDS staging ----
__device__ __forceinline__ void unpackToLds(const u64 q0, const u64 q1, const u64 q2,
                                            u16* __restrict__ stg, int slice,
                                            int ml, int quad) {
  u32 a0 = (u32)q0, a1 = (u32)(q0 >> 32);
  u32 b0 = (u32)q1, b1 = (u32)(q1 >> 32);
  u32 c0 = (u32)q2;
  uint4 F;
  F.x = a0;
  F.y = (a1 & 0xFFFFu) | (b0 << 16);
  F.z = (b0 >> 16) | (b1 << 16);
  F.w = c0;
  *(uint4*)(stg + (((slice << 4) + ml) * 4 + quad) * 8) = F;
}

// ---- wave-split staged gather, ONE ring: wave wv polls+stages slices
// {2wv, 2wv+1}; lane (ml,quad) owns 3 u64 per slice. 4x less MALL traffic
// than all-waves-load-all. Caller must __syncthreads() before reading stg. ----
__device__ __forceinline__ void stageOne(const u64* __restrict__ base, u32 etag,
                                         u16* __restrict__ stg,
                                         int wv, int ml, int quad, int& dead) {
  const int j0 = wv << 1;
  const u64* p0 = base + (u64)j0 * BSTRIDE + ml * 12 + quad * 3;
  const u64* p1 = p0 + BSTRIDE;
  u64 qa0 = ldAtom(p0), qa1 = ldAtom(p0 + 1), qa2 = ldAtom(p0 + 2);
  u64 qb0 = ldAtom(p1), qb1 = ldAtom(p1 + 1), qb2 = ldAtom(p1 + 2);
  int it = 0;
  while (true) {
    u32 badA = (((u32)(qa0 >> 48)) ^ etag) | (((u32)(qa1 >> 48)) ^ etag) |
               (((u32)(qa2 >> 48)) ^ etag);
    u32 badB = (((u32)(qb0 >> 48)) ^ etag) | (((u32)(qb1 >> 48)) ^ etag) |
               (((u32)(qb2 >> 48)) ^ etag);
    if (!__any((badA | badB) != 0)) break;
    if (dead) break;
    if (++it > POLL_BAIL) { dead = 1; break; }
    if (badA) { qa0 = ldAtom(p0); qa1 = ldAtom(p0 + 1); qa2 = ldAtom(p0 + 2); }
    if (badB) { qb0 = ldAtom(p1); qb1 = ldAtom(p1 + 1); qb2 = ldAtom(p1 + 2); }
    if (it > 8) __builtin_amdgcn_s_sleep(1);
  }
  __atomic_signal_fence(__ATOMIC_ACQUIRE);
  unpackToLds(qa0, qa1, qa2, stg, j0, ml, quad);
  unpackToLds(qb0, qb1, qb2, stg, j0 + 1, ml, quad);
}

// ---- wave-split staged gather, BOTH rings fused (L1): one poll loop waits
// on h0 (always ready; ring-buffered) AND h1 (pacing) -> their RTs overlap. ----
__device__ __forceinline__ void stageDual(const u64* __restrict__ b0, u32 e0,
                                          u16* __restrict__ s0,
                                          const u64* __restrict__ b1, u32 e1,
                                          u16* __restrict__ s1, int doH1,
                                          int wv, int ml, int quad, int& dead) {
  const int j0 = wv << 1;
  const int off = ml * 12 + quad * 3;
  const u64* p0a = b0 + (u64)j0 * BSTRIDE + off;
  const u64* p0b = p0a + BSTRIDE;
  const u64* p1a = b1 + (u64)j0 * BSTRIDE + off;
  const u64* p1b = p1a + BSTRIDE;
  u64 xa0 = ldAtom(p0a), xa1 = ldAtom(p0a + 1), xa2 = ldAtom(p0a + 2);
  u64 xb0 = ldAtom(p0b), xb1 = ldAtom(p0b + 1), xb2 = ldAtom(p0b + 2);
  u64 ya0 = 0, ya1 = 0, ya2 = 0, yb0 = 0, yb1 = 0, yb2 = 0;
  if (doH1) {
    ya0 = ldAtom(p1a); ya1 = ldAtom(p1a + 1); ya2 = ldAtom(p1a + 2);
    yb0 = ldAtom(p1b); yb1 = ldAtom(p1b + 1); yb2 = ldAtom(p1b + 2);
  }
  int it = 0;
  while (true) {
    u32 badA = (((u32)(xa0 >> 48)) ^ e0) | (((u32)(xa1 >> 48)) ^ e0) |
               (((u32)(xa2 >> 48)) ^ e0);
    u32 badB = (((u32)(xb0 >> 48)) ^ e0) | (((u32)(xb1 >> 48)) ^ e0) |
               (((u32)(xb2 >> 48)) ^ e0);
    u32 badC = 0, badD = 0;
    if (doH1) {
      badC = (((u32)(ya0 >> 48)) ^ e1) | (((u32)(ya1 >> 48)) ^ e1) |
             (((u32)(ya2 >> 48)) ^ e1);
      badD = (((u32)(yb0 >> 48)) ^ e1) | (((u32)(yb1 >> 48)) ^ e1) |
             (((u32)(yb2 >> 48)) ^ e1);
    }
    if (!__any((badA | badB | badC | badD) != 0)) break;
    if (dead) break;
    if (++it > POLL_BAIL) { dead = 1; break; }
    if (badA) { xa0 = ldAtom(p0a); xa1 = ldAtom(p0a + 1); xa2 = ldAtom(p0a + 2); }
    if (badB) { xb0 = ldAtom(p0b); xb1 = ldAtom(p0b + 1); xb2 = ldAtom(p0b + 2); }
    if (badC) { ya0 = ldAtom(p1a); ya1 = ldAtom(p1a + 1); ya2 = ldAtom(p1a + 2); }
    if (badD) { yb0 = ldAtom(p1b); yb1 = ldAtom(p1b + 1); yb2 = ldAtom(p1b + 2); }
    if (it > 8) __builtin_amdgcn_s_sleep(1);
  }
  __atomic_signal_fence(__ATOMIC_ACQUIRE);
  unpackToLds(xa0, xa1, xa2, s0, j0, ml, quad);
  unpackToLds(xb0, xb1, xb2, s0, j0 + 1, ml, quad);
  if (doH1) {
    unpackToLds(ya0, ya1, ya2, s1, j0, ml, quad);
    unpackToLds(yb0, yb1, yb2, s1, j0 + 1, ml, quad);
  }
}

extern "C" __global__ void __launch_bounds__(256, 1)
lstm_fused(const int* __restrict__ tokens, const void* __restrict__ emb,
           const void* __restrict__ W0, const void* __restrict__ R0, const void* __restrict__ b0,
           const void* __restrict__ W1, const void* __restrict__ R1, const void* __restrict__ b1,
           const void* __restrict__ Wout, const void* __restrict__ bout,
           void* __restrict__ outv) {
  extern __shared__ char smem[];

  const int tid = threadIdx.x;
  const int b = blockIdx.x;
  const int g = b & (NG - 1);
  const int w = b >> 4;
  const int role = w >> 3;             // 0 = layer-0 wg, 1 = layer-1 wg
  const int sl = w & 7;
  const int isF32 = g_isF32;
  const u32 tagB = ((u32)g_run) << 10;

  auto ldf = [&](const void* p, int idx) -> float {
    return isF32 ? ((const float*)p)[idx] : bf2f(((const u16*)p)[idx]);
  };

  const int lane = tid & 63;
  const int wv = tid >> 6;            // wave = gate q (output tiles 2wv, 2wv+1)
  const int ml = lane & 15;
  const int quad = lane >> 4;
  const int um = tid >> 4;
  const int un = tid & 15;

  // cell/post thread mapping: (batch mB, slot uS) ; slot uS<12 holds 3 (or 2)
  // consecutive units: q=uS/3, s=uS%3, kb=8q+3s (s<2: 3 units; s==2: 2 units)
  const int mB = tid >> 4;
  const int uS = tid & 15;
  const int qS = uS / 3;
  const int sS = uS - qS * 3;
  const int kb = (qS << 3) + 3 * sS;
  const int nFull = (sS != 2);

  int* flp = g_pr + (g << 3) * 16;
  int dead = 0;

  if (role == 0) {
    // ================= LAYER-0 WORKGROUP =================
    u16* w0t = (u16*)(smem + L0_W0T);
    u16* r0t = (u16*)(smem + L0_R0T);
    u16* ldsX = (u16*)(smem + L0_X);
    float* ldsG = (float*)(smem + L0_G);
    u16* stg = (u16*)(smem + L0_STG);
    float* ldsB = (float*)(smem + L0_B);

    for (int i = tid; i < 128 * 128; i += 256) {
      int k = i >> 7, n = i & 127;
      int col = ((n >> 5) << 8) + (sl << 5) + (n & 31);
      w0t[n * EPAD + k] = f2bf(ldf(W0, k * 1024 + col));
    }
    for (int i = tid; i < 128 * 256; i += 256) {
      int k = i >> 7, n = i & 127;
      int col = ((n >> 5) << 8) + (sl << 5) + (n & 31);
      r0t[n * HS + k] = f2bf(ldf(R0, k * 1024 + col));
    }
    if (tid < 128) {
      int col = ((tid >> 5) << 8) + (sl << 5) + (tid & 31);
      ldsB[tid] = ldf(b0, col);
    }

    float cst[3] = {0.f, 0.f, 0.f};
    const int tokBase = (g * MB + um) * T_STEPS;
    int prMin = 0;                    // cached min L1 progress (ring guard)

    float4 xfA, xfB; uint4 xbf;
    {
      int tok = tokens[tokBase];
      if (isF32) {
        const float* row = (const float*)emb + (u64)tok * E_SZ + (un << 3);
        xfA = *(const float4*)row; xfB = *(const float4*)(row + 4);
      } else {
        xbf = *(const uint4*)((const u16*)emb + (u64)tok * E_SZ + (un << 3));
      }
    }
    __syncthreads();

    const int row0 = (wv << 5) + ml;
    const u16* brA0 = w0t + row0 * EPAD + (quad << 3);
    const u16* brB0 = brA0 + (EPAD << 4);
    const u16* brA2 = r0t + row0 * HS + (quad << 3);
    const u16* brB2 = brA2 + (HS << 4);

    for (int t = 0; t < T_STEPS; t++) {
      // ring guard at TOP of step: off the post critical path; RT overlaps
      // the x-commit + W0 phase. Amortized via cached prMin.
      if (t >= RD && prMin < t - RD + 1)
        prMin = wavePollMin(flp, t - RD + 1, lane, dead);

      // commit x_t
      {
        uint4 pk;
        if (isF32) {
          pk.x = (u32)f2bf(xfA.x) | ((u32)f2bf(xfA.y) << 16);
          pk.y = (u32)f2bf(xfA.z) | ((u32)f2bf(xfA.w) << 16);
          pk.z = (u32)f2bf(xfB.x) | ((u32)f2bf(xfB.y) << 16);
          pk.w = (u32)f2bf(xfB.z) | ((u32)f2bf(xfB.w) << 16);
        } else pk = xbf;
        *(uint4*)(ldsX + um * EPAD + (un << 3)) = pk;
      }
      __syncthreads();

      float ba = ldsB[row0], bb = ldsB[row0 + 16];
      f32x4 acA = {ba, ba, ba, ba}, acB = {bb, bb, bb, bb};

      // x_t @ W0 (no dependence on h0)
      {
        const u16* ar = ldsX + ml * EPAD + (quad << 3);
#pragma unroll
        for (int kc = 0; kc < 4; kc++) {
          bf16x8 av = *(const bf16x8*)(ar + kc * 32);
          acA = __builtin_amdgcn_mfma_f32_16x16x32_bf16(av, *(const bf16x8*)(brA0 + kc * 32), acA, 0, 0, 0);
          acB = __builtin_amdgcn_mfma_f32_16x16x32_bf16(av, *(const bf16x8*)(brB0 + kc * 32), acB, 0, 0, 0);
        }
      }

      // h0_{t-1}: wave-split staged gather (2 slices/wave) -> LDS -> frags
      if (t > 0) {
        const u64* base = g_exH0 +
            (u64)((((t - 1) & (RD - 1)) * NG + g) * NSL) * BSTRIDE;
        stageOne(base, (tagB + t) & 0xFFFFu, stg, wv, ml, quad, dead);
        __syncthreads();
#pragma unroll
        for (int j = 0; j < NSL; j++) {
          bf16x8 fv = *(const bf16x8*)(stg + (((j << 4) + ml) * 4 + quad) * 8);
          acA = __builtin_amdgcn_mfma_f32_16x16x32_bf16(fv, *(const bf16x8*)(brA2 + (j << 5)), acA, 0, 0, 0);
          acB = __builtin_amdgcn_mfma_f32_16x16x32_bf16(fv, *(const bf16x8*)(brB2 + (j << 5)), acB, 0, 0, 0);
        }
      }

      // gates
#pragma unroll
      for (int r = 0; r < 4; r++) {
        int m = (quad << 2) + r;
        float gA = (wv == 2) ? tnh_(acA[r]) : sig_(acA[r]);
        float gB = (wv == 2) ? tnh_(acB[r]) : sig_(acB[r]);
        ldsG[row0 * 17 + m] = gA;
        ldsG[(row0 + 16) * 17 + m] = gB;
      }
      __syncthreads();

      // cell update -> direct tagged post (fire-and-forget, no fence/flag)
      if (uS < 12) {
        u64 val = ((u64)((tagB + t + 1) & 0xFFFFu)) << 48;
#pragma unroll
        for (int i2 = 0; i2 < 3; i2++) {
          if (i2 < 2 || nFull) {
            int k = kb + i2;
            float iv = ldsG[k * 17 + mB];
            float fv = ldsG[(32 + k) * 17 + mB];
            float gv = ldsG[(64 + k) * 17 + mB];
            float ov = ldsG[(96 + k) * 17 + mB];
            float c = fv * cst[i2] + iv * gv; cst[i2] = c;
            val |= ((u64)f2bf(ov * tnh_(c))) << (16 * i2);
          }
        }
        u64 elem = (u64)(((t & (RD - 1)) * NG + g) * NSL + sl) * BSTRIDE +
                   mB * 12 + uS;
        __hip_atomic_store(g_exH0 + elem, val,
                           __ATOMIC_RELAXED, __HIP_MEMORY_SCOPE_AGENT);
      }

      // x_{t+1} prefetch in flight across next rendezvous
      if (t + 1 < T_STEPS) {
        int tok = tokens[tokBase + t + 1];
        if (isF32) {
          const float* row = (const float*)emb + (u64)tok * E_SZ + (un << 3);
          xfA = *(const float4*)row; xfB = *(const float4*)(row + 4);
        } else {
          xbf = *(const uint4*)((const u16*)emb + (u64)tok * E_SZ + (un << 3));
        }
      }
    }
  } else {
    // ================= LAYER-1 WORKGROUP =================
    u16* w1t = (u16*)(smem + L1_W1T);
    u16* r1t = (u16*)(smem + L1_R1T);
    u16* stg0 = (u16*)(smem + L1_SG0);
    u16* stg1 = (u16*)(smem + L1_SG1);
    float* ldsG = (float*)(smem + L1_G);
    float* ldsB = (float*)(smem + L1_B);

    for (int i = tid; i < 128 * 256; i += 256) {
      int k = i >> 7, n = i & 127;
      int col = ((n >> 5) << 8) + (sl << 5) + (n & 31);
      w1t[n * HS + k] = f2bf(ldf(W1, k * 1024 + col));
      r1t[n * HS + k] = f2bf(ldf(R1, k * 1024 + col));
    }
    if (tid < 128) {
      int col = ((tid >> 5) << 8) + (sl << 5) + (tid & 31);
      ldsB[tid] = ldf(b1, col);
    }
    __syncthreads();

    float cst[3] = {0.f, 0.f, 0.f};
    const int row0 = (wv << 5) + ml;
    const u16* brA1 = w1t + row0 * HS + (quad << 3);
    const u16* brB1 = brA1 + (HS << 4);
    const u16* brA2 = r1t + row0 * HS + (quad << 3);
    const u16* brB2 = brA2 + (HS << 4);

    for (int t = 0; t < T_STEPS; t++) {
      // fused wave-split staged gather: h0_t (ready) + h1_{t-1} (pacing),
      // single poll loop, single barrier -> their RTs fully overlap
      {
        const u64* h0base = g_exH0 +
            (u64)(((t & (RD - 1)) * NG + g) * NSL) * BSTRIDE;
        const u64* h1base = g_exH1 +
            (u64)((((t - 1) & 1) * NG + g) * NSL) * BSTRIDE;
        stageDual(h0base, (tagB + t + 1) & 0xFFFFu, stg0,
                  h1base, (tagB + t) & 0xFFFFu, stg1, (t > 0),
                  wv, ml, quad, dead);
      }
      __syncthreads();

      // ring-slot release immediately after staging: all h0 loads done
      if (tid == 0) {
        __atomic_signal_fence(__ATOMIC_RELEASE);
        __hip_atomic_store(g_pr + ((g << 3) + sl) * 16, t + 1,
                           __ATOMIC_RELAXED, __HIP_MEMORY_SCOPE_AGENT);
      }

      float ba = ldsB[row0], bb = ldsB[row0 + 16];
      f32x4 acA = {ba, ba, ba, ba}, acB = {bb, bb, bb, bb};

      // h0_t @ W1
#pragma unroll
      for (int j = 0; j < NSL; j++) {
        bf16x8 fv = *(const bf16x8*)(stg0 + (((j << 4) + ml) * 4 + quad) * 8);
        acA = __builtin_amdgcn_mfma_f32_16x16x32_bf16(fv, *(const bf16x8*)(brA1 + (j << 5)), acA, 0, 0, 0);
        acB = __builtin_amdgcn_mfma_f32_16x16x32_bf16(fv, *(const bf16x8*)(brB1 + (j << 5)), acB, 0, 0, 0);
      }
      // h1_{t-1} @ R1
      if (t > 0) {
#pragma unroll
        for (int j = 0; j < NSL; j++) {
          bf16x8 fv = *(const bf16x8*)(stg1 + (((j << 4) + ml) * 4 + quad) * 8);
          acA = __builtin_amdgcn_mfma_f32_16x16x32_bf16(fv, *(const bf16x8*)(brA2 + (j << 5)), acA, 0, 0, 0);
          acB = __builtin_amdgcn_mfma_f32_16x16x32_bf16(fv, *(const bf16x8*)(brB2 + (j << 5)), acB, 0, 0, 0);
        }
      }

      // gates
#pragma unroll
      for (int r = 0; r < 4; r++) {
        int m = (quad << 2) + r;
        float gA = (wv == 2) ? tnh_(acA[r]) : sig_(acA[r]);
        float gB = (wv == 2) ? tnh_(acB[r]) : sig_(acB[r]);
        ldsG[row0 * 17 + m] = gA;
        ldsG[(row0 + 16) * 17 + m] = gB;
      }
      __syncthreads();

      // cell update -> direct tagged post
      if (uS < 12) {
        u64 val = ((u64)((tagB + t + 1) & 0xFFFFu)) << 48;
#pragma unroll
        for (int i2 = 0; i2 < 3; i2++) {
          if (i2 < 2 || nFull) {
            int k = kb + i2;
            float iv = ldsG[k * 17 + mB];
            float fv = ldsG[(32 + k) * 17 + mB];
            float gv = ldsG[(64 + k) * 17 + mB];
            float ov = ldsG[(96 + k) * 17 + mB];
            float c = fv * cst[i2] + iv * gv; cst[i2] = c;
            val |= ((u64)f2bf(ov * tnh_(c))) << (16 * i2);
          }
        }
        u64 elem = (u64)(((t & 1) * NG + g) * NSL + sl) * BSTRIDE +
                   mB * 12 + uS;
        __hip_atomic_store(g_exH1 + elem, val,
                           __ATOMIC_RELAXED, __HIP_MEMORY_SCOPE_AGENT);
      }
      __syncthreads();   // protects ldsG(t)/stg(t) reads vs writes(t+1)
    }

    // epilogue: logits from h1_{T-1} (staging buffers reused as gather area)
    if (sl == 0) {
      u16* ldsEpi = stg0;   // 8448B needed <= 16384B of STG0+STG1
      const u32 etag = (tagB + T_STEPS) & 0xFFFFu;
      if (uS < 12) {
        for (int sp = 0; sp < 8; sp++) {
          const u64* p = g_exH1 +
              (u64)(((1) * NG + g) * NSL + sp) * BSTRIDE + mB * 12 + uS;
          u64 v; int it = 0;
          while (true) {
            v = ldAtom(p);
            if ((u32)(v >> 48) == etag) break;
            if (dead) break;
            if (++it > POLL_BAIL) { dead = 1; break; }
            if (it > 8) __builtin_amdgcn_s_sleep(1);
          }
          u16* dst = ldsEpi + mB * HS + (sp << 5) + kb;
          dst[0] = (u16)v;
          dst[1] = (u16)(v >> 16);
          if (nFull) dst[2] = (u16)(v >> 32);
        }
      }
      __syncthreads();
      float* woutf = ldsG;
      float* red = ldsG + 272;
      woutf[tid] = ldf(Wout, tid);
      __syncthreads();
      float p = 0.f;
#pragma unroll
      for (int j = 0; j < 16; j++)
        p += bf2f(ldsEpi[um * HS + (un << 4) + j]) * woutf[(un << 4) + j];
      red[um * 17 + un] = p;
      __syncthreads();
      if (tid < 16) {
        float sum = ldf(bout, 0);
#pragma unroll
        for (int j = 0; j < 16; j++) sum += red[tid * 17 + j];
        float val = sig_(sum);
        if (isF32) ((float*)outv)[g * MB + tid] = val;
        else       ((u16*)outv)[g * MB + tid] = f2bf(val);
      }
    }
  }
}

extern "C" void kernel_launch(void* const* d_in, const int* in_sizes, int n_in,
                              void* d_out, int out_size, void* d_ws, size_t ws_size,
                              hipStream_t stream) {
  const int* tokens = (const int*)d_in[0];
  const void* emb  = d_in[1];
  const void* W0   = d_in[2];
  const void* R0   = d_in[3];
  const void* b0   = d_in[4];
  const void* W1   = d_in[5];
  const void* R1   = d_in[6];
  const void* b1   = d_in[7];
  const void* Wout = d_in[8];
  const void* bout = d_in[9];

  hipFuncSetAttribute((const void*)lstm_fused,
                      hipFuncAttributeMaxDynamicSharedMemorySize, SMEM_TOTAL);

  dtype_probe<<<dim3(1), dim3(256), 0, stream>>>(W0);

  // 256 wgs (16 groups x (8 L0 + 8 L1)), 1 wg/CU: co-resident.
  lstm_fused<<<dim3(256), dim3(256), SMEM_TOTAL, stream>>>(
      tokens, emb, W0, R0, b0, W1, R1, b1, Wout, bout, d_out);
}